// Round 6
// baseline (157.162 us; speedup 1.0000x reference)
//
#include <hip/hip_runtime.h>
#include <math.h>

// Problem constants
#define DMODEL 256
#define NSEQ   512
#define MSEQ   512

// ws layout (float offsets)
#define WS_Q      0            // [512][256]
#define WS_K      131072       // [512][256]
#define WS_V      262144       // [512][256]
#define WS_WPE    393216       // [512][256][4]  (n, d, h)
#define WS_SQK    917504       // [4][512][512]  qk part prescaled, then final scores (in-place)
// total floats = 1966080 -> 7.5 MB

typedef float v4f __attribute__((ext_vector_type(4)));

// ---------------------------------------------------------------------------
// Kernel A: q/k/v projections.  Y = X @ W^T + b   (fp32)
// ---------------------------------------------------------------------------
__global__ __launch_bounds__(256) void proj_qkv(
    const float* __restrict__ xq, const float* __restrict__ xk,
    const float* __restrict__ xv,
    const float* __restrict__ Wq, const float* __restrict__ bq,
    const float* __restrict__ Wk, const float* __restrict__ bk,
    const float* __restrict__ Wv, const float* __restrict__ bv,
    float* __restrict__ ws)
{
    int bid = blockIdx.x;
    int mat = bid >> 6;
    int rb  = bid & 63;
    const float* X; const float* W; const float* b; float* Y;
    if (mat == 0)      { X = xq; W = Wq; b = bq; Y = ws + WS_Q; }
    else if (mat == 1) { X = xk; W = Wk; b = bk; Y = ws + WS_K; }
    else               { X = xv; W = Wv; b = bv; Y = ws + WS_V; }

    int c  = threadIdx.x;
    int r0 = rb * 8;
    float acc[8];
    float bias = b[c];
#pragma unroll
    for (int r = 0; r < 8; ++r) acc[r] = bias;

    const float4* Wrow = (const float4*)(W + (size_t)c * DMODEL);
    for (int d4 = 0; d4 < 64; ++d4) {
        float4 w = Wrow[d4];
#pragma unroll
        for (int r = 0; r < 8; ++r) {
            float4 x = ((const float4*)(X + (size_t)(r0 + r) * DMODEL))[d4];
            acc[r] += w.x * x.x + w.y * x.y + w.z * x.z + w.w * x.w;
        }
    }
#pragma unroll
    for (int r = 0; r < 8; ++r)
        Y[(size_t)(r0 + r) * DMODEL + c] = acc[r];
}

// ---------------------------------------------------------------------------
// Kernel B: W'[n][d][h] = sum_c q[n][c] * Wp[c][d]
// ---------------------------------------------------------------------------
__global__ __launch_bounds__(256) void make_wpeff(
    const float* __restrict__ Wp, float* __restrict__ ws)
{
    const float* q   = ws + WS_Q;
    float*       wpe = ws + WS_WPE;
    int n = blockIdx.x;
    int d = threadIdx.x;

    __shared__ float ql[256];
    ql[d] = q[(size_t)n * DMODEL + d];
    __syncthreads();

    float acc[4];
#pragma unroll
    for (int h = 0; h < 4; ++h) {
        float a = 0.f;
#pragma unroll 8
        for (int dh = 0; dh < 64; ++dh) {
            int c = h * 64 + dh;
            a += ql[c] * Wp[(size_t)c * DMODEL + d];
        }
        acc[h] = a;
    }
    *(float4*)&wpe[(size_t)n * 1024 + d * 4] =
        make_float4(acc[0], acc[1], acc[2], acc[3]);
}

// ---------------------------------------------------------------------------
// Kernel C: sqk[h][n][m] = 0.125 * (q[n,h]·k[m,h] + q[n,h]·bp[h])
// ---------------------------------------------------------------------------
__global__ __launch_bounds__(256) void qk_scores(
    const float* __restrict__ bp, float* __restrict__ ws)
{
    const float* q   = ws + WS_Q;
    const float* k   = ws + WS_K;
    float*       sqk = ws + WS_SQK;

    int bid = blockIdx.x;
    int h   = bid >> 6;
    int g   = bid & 63;
    int n0  = g * 8;
    int tid = threadIdx.x;

    __shared__ float qls[8][64];
    __shared__ float qb[8];

    if (tid < 128) {
        int row = tid >> 4, col = (tid & 15) * 4;
        *(float4*)&qls[row][col] =
            *(const float4*)&q[(size_t)(n0 + row) * DMODEL + h * 64 + col];
    }
    __syncthreads();
    if (tid < 8) {
        float s = 0.f;
        for (int dh = 0; dh < 64; ++dh) s += qls[tid][dh] * bp[h * 64 + dh];
        qb[tid] = s;
    }
    __syncthreads();

    const float* ka = k + (size_t)tid * DMODEL + h * 64;
    const float* kb = ka + (size_t)256 * DMODEL;
    float acca[8] = {};
    float accb[8] = {};
#pragma unroll 4
    for (int d4 = 0; d4 < 16; ++d4) {
        float4 xa = *(const float4*)(ka + d4 * 4);
        float4 xb = *(const float4*)(kb + d4 * 4);
#pragma unroll
        for (int j = 0; j < 8; ++j) {
            float4 qq = *(const float4*)&qls[j][d4 * 4];
            acca[j] += xa.x * qq.x + xa.y * qq.y + xa.z * qq.z + xa.w * qq.w;
            accb[j] += xb.x * qq.x + xb.y * qq.y + xb.z * qq.z + xb.w * qq.w;
        }
    }
#pragma unroll
    for (int j = 0; j < 8; ++j) {
        size_t base = (size_t)h * 262144 + (size_t)(n0 + j) * MSEQ;
        sqk[base + tid]       = 0.125f * (acca[j] + qb[j]);
        sqk[base + tid + 256] = 0.125f * (accb[j] + qb[j]);
    }
}

// ---------------------------------------------------------------------------
// Kernel D: HBM stream via global_load_lds DMA path.
// grid = 2048 blocks (n, m-quarter of 128 rows), 256 threads = 4 independent
// waves (no barriers in the stream loop). Per wave: 32 rows in 4 chunks of 8,
// double-buffered 8 KB LDS buffers, counted vmcnt(8) so 16-24 KB of loads
// stay in flight. Each gload_lds stages one 1 KB row (lane-linear, matches
// consumption: lane l ds_read_b128's element l -> conflict-free, no swizzle).
// Lane holds W'[d=4l..4l+3][h0..3] in regs; 64-lane butterfly per row.
// Epilogue: sqk += 0.125 * result (in place).
// ---------------------------------------------------------------------------
__global__ __launch_bounds__(256) void p_scores(
    const float* __restrict__ Xp, float* __restrict__ ws)
{
    const float* wpe = ws + WS_WPE;
    float*       sqk = ws + WS_SQK;

    int n    = blockIdx.x >> 2;
    int m0   = (blockIdx.x & 3) * 128;
    int tid  = threadIdx.x;
    int wv   = tid >> 6;
    int lane = tid & 63;

    __shared__ float xs[4][2][2048];   // [wave][buf][8 rows x 256 floats] 64 KB
    __shared__ float smv[4][128];      // per-row results [h][local m]

    // lane's W' slice: wreg[c] = W'[n][d = lane*4+c][h0..h3]
    const float4* wp4 = (const float4*)(wpe + (size_t)n * 1024);
    float4 wreg[4];
#pragma unroll
    for (int c = 0; c < 4; ++c) wreg[c] = wp4[lane * 4 + c];

    const float* gbase = Xp + ((size_t)n * MSEQ + m0 + wv * 32) * DMODEL;

#define STAGE(cc, bb)                                                         \
    {                                                                         \
        _Pragma("unroll")                                                     \
        for (int r = 0; r < 8; ++r) {                                         \
            const float* g = gbase + ((cc) * 8 + r) * DMODEL + lane * 4;      \
            float* l = &xs[wv][bb][r * 256];                                  \
            __builtin_amdgcn_global_load_lds(                                 \
                (const __attribute__((address_space(1))) unsigned int*)g,     \
                (__attribute__((address_space(3))) unsigned int*)l, 16, 0, 0);\
        }                                                                     \
    }

#define CONSUME(cc, bb)                                                       \
    {                                                                         \
        _Pragma("unroll")                                                     \
        for (int r = 0; r < 8; ++r) {                                         \
            v4f x = *(const v4f*)&xs[wv][bb][r * 256 + lane * 4];             \
            float p0 = x.x*wreg[0].x + x.y*wreg[1].x + x.z*wreg[2].x + x.w*wreg[3].x; \
            float p1 = x.x*wreg[0].y + x.y*wreg[1].y + x.z*wreg[2].y + x.w*wreg[3].y; \
            float p2 = x.x*wreg[0].z + x.y*wreg[1].z + x.z*wreg[2].z + x.w*wreg[3].z; \
            float p3 = x.x*wreg[0].w + x.y*wreg[1].w + x.z*wreg[2].w + x.w*wreg[3].w; \
            _Pragma("unroll")                                                 \
            for (int off = 1; off < 64; off <<= 1) {                          \
                p0 += __shfl_xor(p0, off);                                    \
                p1 += __shfl_xor(p1, off);                                    \
                p2 += __shfl_xor(p2, off);                                    \
                p3 += __shfl_xor(p3, off);                                    \
            }                                                                 \
            if (lane == 0) {                                                  \
                int ml = wv * 32 + (cc) * 8 + r;                              \
                smv[0][ml] = p0; smv[1][ml] = p1;                             \
                smv[2][ml] = p2; smv[3][ml] = p3;                             \
            }                                                                 \
        }                                                                     \
    }

    STAGE(0, 0)
    STAGE(1, 1)

    asm volatile("s_waitcnt vmcnt(8)" ::: "memory");   // chunk0 landed
    __builtin_amdgcn_sched_barrier(0);
    CONSUME(0, 0)
    __builtin_amdgcn_sched_barrier(0);
    STAGE(2, 0)

    asm volatile("s_waitcnt vmcnt(8)" ::: "memory");   // chunk1 landed
    __builtin_amdgcn_sched_barrier(0);
    CONSUME(1, 1)
    __builtin_amdgcn_sched_barrier(0);
    STAGE(3, 1)

    asm volatile("s_waitcnt vmcnt(8)" ::: "memory");   // chunk2 landed
    __builtin_amdgcn_sched_barrier(0);
    CONSUME(2, 0)

    asm volatile("s_waitcnt vmcnt(0)" ::: "memory");   // chunk3 landed
    __builtin_amdgcn_sched_barrier(0);
    CONSUME(3, 1)

#undef STAGE
#undef CONSUME

    __syncthreads();
    if (tid < 128) {
        size_t ob = (size_t)n * MSEQ + m0 + tid;
#pragma unroll
        for (int h = 0; h < 4; ++h)
            sqk[h * 262144 + ob] += 0.125f * smv[h][tid];
    }
}

// ---------------------------------------------------------------------------
// Kernel E: masked softmax over m + attn @ v, writes final output.
// ---------------------------------------------------------------------------
__global__ __launch_bounds__(256) void softmax_av(
    const unsigned char* __restrict__ mask,
    float* __restrict__ out, float* __restrict__ ws)
{
    const float* v      = ws + WS_V;
    const float* scores = ws + WS_SQK;

    int bid = blockIdx.x;
    int h   = bid >> 6;
    int g   = bid & 63;
    int n0  = g * 8;

    __shared__ float  pl[MSEQ * 8];   // [m][j]  16 KB
    __shared__ float4 red4[256];      // reduce scratch 4 KB
    __shared__ float  wred[4];

    int tid  = threadIdx.x;
    int lane = tid & 63, wv = tid >> 6;

    for (int j = 0; j < 8; ++j) {
        int n = n0 + j;
        const float* srow = scores + (size_t)h * 262144 + (size_t)n * MSEQ;
        float s0 = srow[tid];
        float s1 = srow[tid + 256];
        if (mask[tid])       s0 = -INFINITY;
        if (mask[tid + 256]) s1 = -INFINITY;

        float mx = fmaxf(s0, s1);
#pragma unroll
        for (int off = 32; off; off >>= 1) mx = fmaxf(mx, __shfl_xor(mx, off));
        if (lane == 0) wred[wv] = mx;
        __syncthreads();
        mx = fmaxf(fmaxf(wred[0], wred[1]), fmaxf(wred[2], wred[3]));

        float e0 = __expf(s0 - mx);
        float e1 = __expf(s1 - mx);
        float sm = e0 + e1;
#pragma unroll
        for (int off = 32; off; off >>= 1) sm += __shfl_xor(sm, off);
        __syncthreads();
        if (lane == 0) wred[wv] = sm;
        __syncthreads();
        sm = wred[0] + wred[1] + wred[2] + wred[3];
        float rinv = 1.0f / sm;

        pl[(size_t)tid * 8 + j]         = e0 * rinv;
        pl[(size_t)(tid + 256) * 8 + j] = e1 * rinv;
        __syncthreads();
    }

    // AV: thread = (dhq 0..15, mq 0..15); each covers 32 m values.
    int dhq = tid & 15, mq = tid >> 4;
    float acc[8][4] = {};
    for (int i = 0; i < 32; ++i) {
        int m = mq * 32 + i;
        float4 vv = *(const float4*)&v[(size_t)m * DMODEL + h * 64 + dhq * 4];
        float4 pa = *(const float4*)&pl[m * 8];
        float4 pb = *(const float4*)&pl[m * 8 + 4];
#pragma unroll
        for (int j = 0; j < 4; ++j) {
            float pv = (&pa.x)[j];
            acc[j][0] += pv * vv.x; acc[j][1] += pv * vv.y;
            acc[j][2] += pv * vv.z; acc[j][3] += pv * vv.w;
        }
#pragma unroll
        for (int j = 0; j < 4; ++j) {
            float pv = (&pb.x)[j];
            acc[4 + j][0] += pv * vv.x; acc[4 + j][1] += pv * vv.y;
            acc[4 + j][2] += pv * vv.z; acc[4 + j][3] += pv * vv.w;
        }
    }

    for (int j = 0; j < 8; ++j) {
        red4[mq * 16 + dhq] =
            make_float4(acc[j][0], acc[j][1], acc[j][2], acc[j][3]);
        __syncthreads();
        if (tid < 64) {
            int dq = tid >> 2, x = tid & 3;
            float s = 0.f;
#pragma unroll
            for (int qq = 0; qq < 16; ++qq)
                s += ((const float*)&red4[qq * 16 + dq])[x];
            out[(size_t)(n0 + j) * DMODEL + h * 64 + tid] = s;
        }
        __syncthreads();
    }
}

// ---------------------------------------------------------------------------
extern "C" void kernel_launch(void* const* d_in, const int* in_sizes, int n_in,
                              void* d_out, int out_size, void* d_ws,
                              size_t ws_size, hipStream_t stream)
{
    const float* xq = (const float*)d_in[0];
    const float* xk = (const float*)d_in[1];
    const float* xv = (const float*)d_in[2];
    const float* xp = (const float*)d_in[3];
    const unsigned char* mask = (const unsigned char*)d_in[4];
    const float* Wq = (const float*)d_in[5];
    const float* bq = (const float*)d_in[6];
    const float* Wk = (const float*)d_in[7];
    const float* bk = (const float*)d_in[8];
    const float* Wv = (const float*)d_in[9];
    const float* bv = (const float*)d_in[10];
    const float* Wp = (const float*)d_in[11];
    const float* bp = (const float*)d_in[12];
    float* out = (float*)d_out;
    float* ws  = (float*)d_ws;

    proj_qkv  <<<192,  256, 0, stream>>>(xq, xk, xv, Wq, bq, Wk, bk, Wv, bv, ws);
    make_wpeff<<<512,  256, 0, stream>>>(Wp, ws);
    qk_scores <<<256,  256, 0, stream>>>(bp, ws);
    p_scores  <<<2048, 256, 0, stream>>>(xp, ws);
    softmax_av<<<256,  256, 0, stream>>>(mask, out, ws);
}

// Round 7
// 115.404 us; speedup vs baseline: 1.3618x; 1.3618x over previous
//
#include <hip/hip_runtime.h>
#include <math.h>

// Problem constants
#define DMODEL 256
#define NSEQ   512
#define MSEQ   512

// ws layout (float offsets)
#define WS_Q      0            // [512][256]
#define WS_K      131072       // [512][256]
#define WS_V      262144       // [512][256]
#define WS_WPE    393216       // [512][256][4]  (n, d, h)
#define WS_SQK    917504       // [4][512][512]  qk part prescaled, then final scores (in-place)
// total floats = 1966080 -> 7.5 MB

typedef float v4f __attribute__((ext_vector_type(4)));

// ---------------------------------------------------------------------------
// Kernel A: q/k/v projections.  Y = X @ W^T + b   (fp32)
// ---------------------------------------------------------------------------
__global__ __launch_bounds__(256) void proj_qkv(
    const float* __restrict__ xq, const float* __restrict__ xk,
    const float* __restrict__ xv,
    const float* __restrict__ Wq, const float* __restrict__ bq,
    const float* __restrict__ Wk, const float* __restrict__ bk,
    const float* __restrict__ Wv, const float* __restrict__ bv,
    float* __restrict__ ws)
{
    int bid = blockIdx.x;
    int mat = bid >> 6;
    int rb  = bid & 63;
    const float* X; const float* W; const float* b; float* Y;
    if (mat == 0)      { X = xq; W = Wq; b = bq; Y = ws + WS_Q; }
    else if (mat == 1) { X = xk; W = Wk; b = bk; Y = ws + WS_K; }
    else               { X = xv; W = Wv; b = bv; Y = ws + WS_V; }

    int c  = threadIdx.x;
    int r0 = rb * 8;
    float acc[8];
    float bias = b[c];
#pragma unroll
    for (int r = 0; r < 8; ++r) acc[r] = bias;

    const float4* Wrow = (const float4*)(W + (size_t)c * DMODEL);
    for (int d4 = 0; d4 < 64; ++d4) {
        float4 w = Wrow[d4];
#pragma unroll
        for (int r = 0; r < 8; ++r) {
            float4 x = ((const float4*)(X + (size_t)(r0 + r) * DMODEL))[d4];
            acc[r] += w.x * x.x + w.y * x.y + w.z * x.z + w.w * x.w;
        }
    }
#pragma unroll
    for (int r = 0; r < 8; ++r)
        Y[(size_t)(r0 + r) * DMODEL + c] = acc[r];
}

// ---------------------------------------------------------------------------
// Kernel B: W'[n][d][h] = sum_c q[n][c] * Wp[c][d]
// ---------------------------------------------------------------------------
__global__ __launch_bounds__(256) void make_wpeff(
    const float* __restrict__ Wp, float* __restrict__ ws)
{
    const float* q   = ws + WS_Q;
    float*       wpe = ws + WS_WPE;
    int n = blockIdx.x;
    int d = threadIdx.x;

    __shared__ float ql[256];
    ql[d] = q[(size_t)n * DMODEL + d];
    __syncthreads();

    float acc[4];
#pragma unroll
    for (int h = 0; h < 4; ++h) {
        float a = 0.f;
#pragma unroll 8
        for (int dh = 0; dh < 64; ++dh) {
            int c = h * 64 + dh;
            a += ql[c] * Wp[(size_t)c * DMODEL + d];
        }
        acc[h] = a;
    }
    *(float4*)&wpe[(size_t)n * 1024 + d * 4] =
        make_float4(acc[0], acc[1], acc[2], acc[3]);
}

// ---------------------------------------------------------------------------
// Kernel C: sqk[h][n][m] = 0.125 * (q[n,h]·k[m,h] + q[n,h]·bp[h])
// ---------------------------------------------------------------------------
__global__ __launch_bounds__(256) void qk_scores(
    const float* __restrict__ bp, float* __restrict__ ws)
{
    const float* q   = ws + WS_Q;
    const float* k   = ws + WS_K;
    float*       sqk = ws + WS_SQK;

    int bid = blockIdx.x;
    int h   = bid >> 6;
    int g   = bid & 63;
    int n0  = g * 8;
    int tid = threadIdx.x;

    __shared__ float qls[8][64];
    __shared__ float qb[8];

    if (tid < 128) {
        int row = tid >> 4, col = (tid & 15) * 4;
        *(float4*)&qls[row][col] =
            *(const float4*)&q[(size_t)(n0 + row) * DMODEL + h * 64 + col];
    }
    __syncthreads();
    if (tid < 8) {
        float s = 0.f;
        for (int dh = 0; dh < 64; ++dh) s += qls[tid][dh] * bp[h * 64 + dh];
        qb[tid] = s;
    }
    __syncthreads();

    const float* ka = k + (size_t)tid * DMODEL + h * 64;
    const float* kb = ka + (size_t)256 * DMODEL;
    float acca[8] = {};
    float accb[8] = {};
#pragma unroll 4
    for (int d4 = 0; d4 < 16; ++d4) {
        float4 xa = *(const float4*)(ka + d4 * 4);
        float4 xb = *(const float4*)(kb + d4 * 4);
#pragma unroll
        for (int j = 0; j < 8; ++j) {
            float4 qq = *(const float4*)&qls[j][d4 * 4];
            acca[j] += xa.x * qq.x + xa.y * qq.y + xa.z * qq.z + xa.w * qq.w;
            accb[j] += xb.x * qq.x + xb.y * qq.y + xb.z * qq.z + xb.w * qq.w;
        }
    }
#pragma unroll
    for (int j = 0; j < 8; ++j) {
        size_t base = (size_t)h * 262144 + (size_t)(n0 + j) * MSEQ;
        sqk[base + tid]       = 0.125f * (acca[j] + qb[j]);
        sqk[base + tid + 256] = 0.125f * (accb[j] + qb[j]);
    }
}

// ---------------------------------------------------------------------------
// Kernel D: HBM-streaming kernel, MAX-OCCUPANCY variant.
// grid = 2048 blocks (n, m-chunk of 128 rows) = 8 blocks/CU; 256 threads,
// thread = (local row ml, d-half): streams 512 B (32 float4, ~8 in flight).
// __launch_bounds__(256,8) forces <=64 VGPR -> 32 waves/CU (8/SIMD), the
// RMSNorm-like regime that measured 4.89 TB/s read on this chip.
// Halves combine via shfl_xor(1); epilogue: sqk += 0.125 * result.
// ---------------------------------------------------------------------------
__global__ __launch_bounds__(256, 8) void p_scores(
    const float* __restrict__ Xp, float* __restrict__ ws)
{
    const float* wpe = ws + WS_WPE;
    float*       sqk = ws + WS_SQK;

    int n    = blockIdx.x >> 2;
    int m0   = (blockIdx.x & 3) * 128;
    int tid  = threadIdx.x;
    int ml   = tid >> 1;          // local row 0..127
    int half = tid & 1;           // d-half

    __shared__ float4 wl[256];    // W'[n]: wl[d4*4+c] spans d, holds (h0..h3)
    __shared__ float  smv[4][128];

    wl[tid] = ((const float4*)(wpe + (size_t)n * 1024))[tid];
    __syncthreads();

    const v4f* __restrict__ xrow =
        (const v4f*)(Xp + ((size_t)n * MSEQ + m0 + ml) * DMODEL) + half * 32;
    const float4* wbase = wl + half * 128;

    float s0 = 0.f, s1 = 0.f, s2 = 0.f, s3 = 0.f;
#pragma unroll 8
    for (int i = 0; i < 32; ++i) {
        v4f x = xrow[i];
        float4 w0 = wbase[i * 4 + 0];
        float4 w1 = wbase[i * 4 + 1];
        float4 w2 = wbase[i * 4 + 2];
        float4 w3 = wbase[i * 4 + 3];
        s0 += x.x * w0.x + x.y * w1.x + x.z * w2.x + x.w * w3.x;
        s1 += x.x * w0.y + x.y * w1.y + x.z * w2.y + x.w * w3.y;
        s2 += x.x * w0.z + x.y * w1.z + x.z * w2.z + x.w * w3.z;
        s3 += x.x * w0.w + x.y * w1.w + x.z * w2.w + x.w * w3.w;
    }

    // combine d-halves (lanes 2m / 2m+1)
    s0 += __shfl_xor(s0, 1);
    s1 += __shfl_xor(s1, 1);
    s2 += __shfl_xor(s2, 1);
    s3 += __shfl_xor(s3, 1);
    if (half == 0) {
        smv[0][ml] = s0; smv[1][ml] = s1;
        smv[2][ml] = s2; smv[3][ml] = s3;
    }
    __syncthreads();

    if (tid < 128) {
        size_t ob = (size_t)n * MSEQ + m0 + tid;
#pragma unroll
        for (int h = 0; h < 4; ++h)
            sqk[h * 262144 + ob] += 0.125f * smv[h][tid];
    }
}

// ---------------------------------------------------------------------------
// Kernel E: masked softmax over m + attn @ v, writes final output.
// ---------------------------------------------------------------------------
__global__ __launch_bounds__(256) void softmax_av(
    const unsigned char* __restrict__ mask,
    float* __restrict__ out, float* __restrict__ ws)
{
    const float* v      = ws + WS_V;
    const float* scores = ws + WS_SQK;

    int bid = blockIdx.x;
    int h   = bid >> 6;
    int g   = bid & 63;
    int n0  = g * 8;

    __shared__ float  pl[MSEQ * 8];   // [m][j]  16 KB
    __shared__ float4 red4[256];      // reduce scratch 4 KB
    __shared__ float  wred[4];

    int tid  = threadIdx.x;
    int lane = tid & 63, wv = tid >> 6;

    for (int j = 0; j < 8; ++j) {
        int n = n0 + j;
        const float* srow = scores + (size_t)h * 262144 + (size_t)n * MSEQ;
        float s0 = srow[tid];
        float s1 = srow[tid + 256];
        if (mask[tid])       s0 = -INFINITY;
        if (mask[tid + 256]) s1 = -INFINITY;

        float mx = fmaxf(s0, s1);
#pragma unroll
        for (int off = 32; off; off >>= 1) mx = fmaxf(mx, __shfl_xor(mx, off));
        if (lane == 0) wred[wv] = mx;
        __syncthreads();
        mx = fmaxf(fmaxf(wred[0], wred[1]), fmaxf(wred[2], wred[3]));

        float e0 = __expf(s0 - mx);
        float e1 = __expf(s1 - mx);
        float sm = e0 + e1;
#pragma unroll
        for (int off = 32; off; off >>= 1) sm += __shfl_xor(sm, off);
        __syncthreads();
        if (lane == 0) wred[wv] = sm;
        __syncthreads();
        sm = wred[0] + wred[1] + wred[2] + wred[3];
        float rinv = 1.0f / sm;

        pl[(size_t)tid * 8 + j]         = e0 * rinv;
        pl[(size_t)(tid + 256) * 8 + j] = e1 * rinv;
        __syncthreads();
    }

    // AV: thread = (dhq 0..15, mq 0..15); each covers 32 m values.
    int dhq = tid & 15, mq = tid >> 4;
    float acc[8][4] = {};
    for (int i = 0; i < 32; ++i) {
        int m = mq * 32 + i;
        float4 vv = *(const float4*)&v[(size_t)m * DMODEL + h * 64 + dhq * 4];
        float4 pa = *(const float4*)&pl[m * 8];
        float4 pb = *(const float4*)&pl[m * 8 + 4];
#pragma unroll
        for (int j = 0; j < 4; ++j) {
            float pv = (&pa.x)[j];
            acc[j][0] += pv * vv.x; acc[j][1] += pv * vv.y;
            acc[j][2] += pv * vv.z; acc[j][3] += pv * vv.w;
        }
#pragma unroll
        for (int j = 0; j < 4; ++j) {
            float pv = (&pb.x)[j];
            acc[4 + j][0] += pv * vv.x; acc[4 + j][1] += pv * vv.y;
            acc[4 + j][2] += pv * vv.z; acc[4 + j][3] += pv * vv.w;
        }
    }

    for (int j = 0; j < 8; ++j) {
        red4[mq * 16 + dhq] =
            make_float4(acc[j][0], acc[j][1], acc[j][2], acc[j][3]);
        __syncthreads();
        if (tid < 64) {
            int dq = tid >> 2, x = tid & 3;
            float s = 0.f;
#pragma unroll
            for (int qq = 0; qq < 16; ++qq)
                s += ((const float*)&red4[qq * 16 + dq])[x];
            out[(size_t)(n0 + j) * DMODEL + h * 64 + tid] = s;
        }
        __syncthreads();
    }
}

// ---------------------------------------------------------------------------
extern "C" void kernel_launch(void* const* d_in, const int* in_sizes, int n_in,
                              void* d_out, int out_size, void* d_ws,
                              size_t ws_size, hipStream_t stream)
{
    const float* xq = (const float*)d_in[0];
    const float* xk = (const float*)d_in[1];
    const float* xv = (const float*)d_in[2];
    const float* xp = (const float*)d_in[3];
    const unsigned char* mask = (const unsigned char*)d_in[4];
    const float* Wq = (const float*)d_in[5];
    const float* bq = (const float*)d_in[6];
    const float* Wk = (const float*)d_in[7];
    const float* bk = (const float*)d_in[8];
    const float* Wv = (const float*)d_in[9];
    const float* bv = (const float*)d_in[10];
    const float* Wp = (const float*)d_in[11];
    const float* bp = (const float*)d_in[12];
    float* out = (float*)d_out;
    float* ws  = (float*)d_ws;

    proj_qkv  <<<192,  256, 0, stream>>>(xq, xk, xv, Wq, bq, Wk, bk, Wv, bv, ws);
    make_wpeff<<<512,  256, 0, stream>>>(Wp, ws);
    qk_scores <<<256,  256, 0, stream>>>(bp, ws);
    p_scores  <<<2048, 256, 0, stream>>>(xp, ws);
    softmax_av<<<256,  256, 0, stream>>>(mask, out, ws);
}

// Round 8
// 111.884 us; speedup vs baseline: 1.4047x; 1.0315x over previous
//
#include <hip/hip_runtime.h>
#include <math.h>

// Problem constants
#define DMODEL 256
#define NSEQ   512
#define MSEQ   512

// ws layout (float offsets)
#define WS_Q      0            // [512][256]
#define WS_K      131072       // [512][256]
#define WS_V      262144       // [512][256]
#define WS_WPE    393216       // [512][256][4]  (n, d, h)
#define WS_SQK    917504       // [4][512][512]  qk prescaled, then final scores (in-place)
// total floats = 1966080 -> 7.5 MB

typedef float v4f __attribute__((ext_vector_type(4)));

// ---------------------------------------------------------------------------
// Kernel A: q/k/v projections.  Y = X @ W^T + b   (fp32)
// ---------------------------------------------------------------------------
__global__ __launch_bounds__(256) void proj_qkv(
    const float* __restrict__ xq, const float* __restrict__ xk,
    const float* __restrict__ xv,
    const float* __restrict__ Wq, const float* __restrict__ bq,
    const float* __restrict__ Wk, const float* __restrict__ bk,
    const float* __restrict__ Wv, const float* __restrict__ bv,
    float* __restrict__ ws)
{
    int bid = blockIdx.x;
    int mat = bid >> 6;
    int rb  = bid & 63;
    const float* X; const float* W; const float* b; float* Y;
    if (mat == 0)      { X = xq; W = Wq; b = bq; Y = ws + WS_Q; }
    else if (mat == 1) { X = xk; W = Wk; b = bk; Y = ws + WS_K; }
    else               { X = xv; W = Wv; b = bv; Y = ws + WS_V; }

    int c  = threadIdx.x;
    int r0 = rb * 8;
    float acc[8];
    float bias = b[c];
#pragma unroll
    for (int r = 0; r < 8; ++r) acc[r] = bias;

    const float4* Wrow = (const float4*)(W + (size_t)c * DMODEL);
    for (int d4 = 0; d4 < 64; ++d4) {
        float4 w = Wrow[d4];
#pragma unroll
        for (int r = 0; r < 8; ++r) {
            float4 x = ((const float4*)(X + (size_t)(r0 + r) * DMODEL))[d4];
            acc[r] += w.x * x.x + w.y * x.y + w.z * x.z + w.w * x.w;
        }
    }
#pragma unroll
    for (int r = 0; r < 8; ++r)
        Y[(size_t)(r0 + r) * DMODEL + c] = acc[r];
}

// ---------------------------------------------------------------------------
// Kernel B: W'[n][d][h] = sum_c q[n][c] * Wp[c][d]
// ---------------------------------------------------------------------------
__global__ __launch_bounds__(256) void make_wpeff(
    const float* __restrict__ Wp, float* __restrict__ ws)
{
    const float* q   = ws + WS_Q;
    float*       wpe = ws + WS_WPE;
    int n = blockIdx.x;
    int d = threadIdx.x;

    __shared__ float ql[256];
    ql[d] = q[(size_t)n * DMODEL + d];
    __syncthreads();

    float acc[4];
#pragma unroll
    for (int h = 0; h < 4; ++h) {
        float a = 0.f;
#pragma unroll 8
        for (int dh = 0; dh < 64; ++dh) {
            int c = h * 64 + dh;
            a += ql[c] * Wp[(size_t)c * DMODEL + d];
        }
        acc[h] = a;
    }
    *(float4*)&wpe[(size_t)n * 1024 + d * 4] =
        make_float4(acc[0], acc[1], acc[2], acc[3]);
}

// ---------------------------------------------------------------------------
// Kernel C: sqk[h][n][m] = 0.125 * (q[n,h]·k[m,h] + q[n,h]·bp[h])
// ---------------------------------------------------------------------------
__global__ __launch_bounds__(256) void qk_scores(
    const float* __restrict__ bp, float* __restrict__ ws)
{
    const float* q   = ws + WS_Q;
    const float* k   = ws + WS_K;
    float*       sqk = ws + WS_SQK;

    int bid = blockIdx.x;
    int h   = bid >> 6;
    int g   = bid & 63;
    int n0  = g * 8;
    int tid = threadIdx.x;

    __shared__ float qls[8][64];
    __shared__ float qb[8];

    if (tid < 128) {
        int row = tid >> 4, col = (tid & 15) * 4;
        *(float4*)&qls[row][col] =
            *(const float4*)&q[(size_t)(n0 + row) * DMODEL + h * 64 + col];
    }
    __syncthreads();
    if (tid < 8) {
        float s = 0.f;
        for (int dh = 0; dh < 64; ++dh) s += qls[tid][dh] * bp[h * 64 + dh];
        qb[tid] = s;
    }
    __syncthreads();

    const float* ka = k + (size_t)tid * DMODEL + h * 64;
    const float* kb = ka + (size_t)256 * DMODEL;
    float acca[8] = {};
    float accb[8] = {};
#pragma unroll 4
    for (int d4 = 0; d4 < 16; ++d4) {
        float4 xa = *(const float4*)(ka + d4 * 4);
        float4 xb = *(const float4*)(kb + d4 * 4);
#pragma unroll
        for (int j = 0; j < 8; ++j) {
            float4 qq = *(const float4*)&qls[j][d4 * 4];
            acca[j] += xa.x * qq.x + xa.y * qq.y + xa.z * qq.z + xa.w * qq.w;
            accb[j] += xb.x * qq.x + xb.y * qq.y + xb.z * qq.z + xb.w * qq.w;
        }
    }
#pragma unroll
    for (int j = 0; j < 8; ++j) {
        size_t base = (size_t)h * 262144 + (size_t)(n0 + j) * MSEQ;
        sqk[base + tid]       = 0.125f * (acca[j] + qb[j]);
        sqk[base + tid + 256] = 0.125f * (accb[j] + qb[j]);
    }
}

// ---------------------------------------------------------------------------
// Kernel D: HBM stream with L1-BYPASS (sc0) loads.
// R1's best-measured per-lane-row shape (thread = m-row, 1 KB), but every
// load is inline-asm global_load_dwordx4 ... sc0 (device-coherent -> skips
// TCP/L1 miss tracking, the hypothesized ~3.2 TB/s limiter). 8-load batches,
// two register sets double-buffered, counted s_waitcnt vmcnt(8) + mandatory
// sched_barrier(0) fence after each wait (guide rule #18).
// Epilogue: sqk += 0.125 * (p . W') in place.  grid = 1024 x 256.
// ---------------------------------------------------------------------------
#define GLD(dst, OFF)                                                     \
    asm volatile("global_load_dwordx4 %0, %1, off offset:%c2 sc0"         \
                 : "=&v"(dst) : "v"(xrow), "n"(OFF))

#define ISSUE(r, B)                                                       \
    GLD(r##0, (B) + 0);   GLD(r##1, (B) + 16);  GLD(r##2, (B) + 32);      \
    GLD(r##3, (B) + 48);  GLD(r##4, (B) + 64);  GLD(r##5, (B) + 80);      \
    GLD(r##6, (B) + 96);  GLD(r##7, (B) + 112);

#define WAITV(N)                                                          \
    asm volatile("s_waitcnt vmcnt(" #N ")" ::: "memory");                 \
    __builtin_amdgcn_sched_barrier(0)

#define CONS(r, K)                                                        \
    acc1(r##0, (K) + 0); acc1(r##1, (K) + 1); acc1(r##2, (K) + 2);        \
    acc1(r##3, (K) + 3); acc1(r##4, (K) + 4); acc1(r##5, (K) + 5);        \
    acc1(r##6, (K) + 6); acc1(r##7, (K) + 7);

__global__ __launch_bounds__(256) void p_scores(
    const float* __restrict__ Xp, float* __restrict__ ws)
{
    const float* wpe = ws + WS_WPE;
    float*       sqk = ws + WS_SQK;

    int n = blockIdx.x >> 1;
    int m = (blockIdx.x & 1) * 256 + threadIdx.x;

    __shared__ float4 wl[256];  // W'[n]: wl[d4*4+c] = (h0,h1,h2,h3) at d=4*d4+c
    wl[threadIdx.x] = ((const float4*)(wpe + (size_t)n * 1024))[threadIdx.x];
    __syncthreads();

    const float* xrow = Xp + ((size_t)n * MSEQ + m) * DMODEL;

    float s0 = 0.f, s1 = 0.f, s2 = 0.f, s3 = 0.f;
    auto acc1 = [&](v4f x, int d4) {
        float4 w0 = wl[d4 * 4 + 0];
        float4 w1 = wl[d4 * 4 + 1];
        float4 w2 = wl[d4 * 4 + 2];
        float4 w3 = wl[d4 * 4 + 3];
        s0 += x.x * w0.x + x.y * w1.x + x.z * w2.x + x.w * w3.x;
        s1 += x.x * w0.y + x.y * w1.y + x.z * w2.y + x.w * w3.y;
        s2 += x.x * w0.z + x.y * w1.z + x.z * w2.z + x.w * w3.z;
        s3 += x.x * w0.w + x.y * w1.w + x.z * w2.w + x.w * w3.w;
    };

    v4f a0, a1, a2, a3, a4, a5, a6, a7;
    v4f b0, b1, b2, b3, b4, b5, b6, b7;

    ISSUE(a, 0)                       // batch 0
    ISSUE(b, 128)                     // batch 1
    WAITV(8);  CONS(a, 0)  ISSUE(a, 256)   // consume 0, issue 2
    WAITV(8);  CONS(b, 8)  ISSUE(b, 384)   // consume 1, issue 3
    WAITV(8);  CONS(a, 16) ISSUE(a, 512)   // consume 2, issue 4
    WAITV(8);  CONS(b, 24) ISSUE(b, 640)   // consume 3, issue 5
    WAITV(8);  CONS(a, 32) ISSUE(a, 768)   // consume 4, issue 6
    WAITV(8);  CONS(b, 40) ISSUE(b, 896)   // consume 5, issue 7
    WAITV(8);  CONS(a, 48)                 // consume 6
    WAITV(0);  CONS(b, 56)                 // consume 7

    size_t ob = (size_t)n * MSEQ + m;
    sqk[0 * 262144 + ob] += 0.125f * s0;
    sqk[1 * 262144 + ob] += 0.125f * s1;
    sqk[2 * 262144 + ob] += 0.125f * s2;
    sqk[3 * 262144 + ob] += 0.125f * s3;
}

#undef GLD
#undef ISSUE
#undef WAITV
#undef CONS

// ---------------------------------------------------------------------------
// Kernel E: masked softmax over m + attn @ v, writes final output.
// ---------------------------------------------------------------------------
__global__ __launch_bounds__(256) void softmax_av(
    const unsigned char* __restrict__ mask,
    float* __restrict__ out, float* __restrict__ ws)
{
    const float* v      = ws + WS_V;
    const float* scores = ws + WS_SQK;

    int bid = blockIdx.x;
    int h   = bid >> 6;
    int g   = bid & 63;
    int n0  = g * 8;

    __shared__ float  pl[MSEQ * 8];   // [m][j]  16 KB
    __shared__ float4 red4[256];      // reduce scratch 4 KB
    __shared__ float  wred[4];

    int tid  = threadIdx.x;
    int lane = tid & 63, wv = tid >> 6;

    for (int j = 0; j < 8; ++j) {
        int n = n0 + j;
        const float* srow = scores + (size_t)h * 262144 + (size_t)n * MSEQ;
        float s0 = srow[tid];
        float s1 = srow[tid + 256];
        if (mask[tid])       s0 = -INFINITY;
        if (mask[tid + 256]) s1 = -INFINITY;

        float mx = fmaxf(s0, s1);
#pragma unroll
        for (int off = 32; off; off >>= 1) mx = fmaxf(mx, __shfl_xor(mx, off));
        if (lane == 0) wred[wv] = mx;
        __syncthreads();
        mx = fmaxf(fmaxf(wred[0], wred[1]), fmaxf(wred[2], wred[3]));

        float e0 = __expf(s0 - mx);
        float e1 = __expf(s1 - mx);
        float sm = e0 + e1;
#pragma unroll
        for (int off = 32; off; off >>= 1) sm += __shfl_xor(sm, off);
        __syncthreads();
        if (lane == 0) wred[wv] = sm;
        __syncthreads();
        sm = wred[0] + wred[1] + wred[2] + wred[3];
        float rinv = 1.0f / sm;

        pl[(size_t)tid * 8 + j]         = e0 * rinv;
        pl[(size_t)(tid + 256) * 8 + j] = e1 * rinv;
        __syncthreads();
    }

    // AV: thread = (dhq 0..15, mq 0..15); each covers 32 m values.
    int dhq = tid & 15, mq = tid >> 4;
    float acc[8][4] = {};
    for (int i = 0; i < 32; ++i) {
        int m = mq * 32 + i;
        float4 vv = *(const float4*)&v[(size_t)m * DMODEL + h * 64 + dhq * 4];
        float4 pa = *(const float4*)&pl[m * 8];
        float4 pb = *(const float4*)&pl[m * 8 + 4];
#pragma unroll
        for (int j = 0; j < 4; ++j) {
            float pv = (&pa.x)[j];
            acc[j][0] += pv * vv.x; acc[j][1] += pv * vv.y;
            acc[j][2] += pv * vv.z; acc[j][3] += pv * vv.w;
        }
#pragma unroll
        for (int j = 0; j < 4; ++j) {
            float pv = (&pb.x)[j];
            acc[4 + j][0] += pv * vv.x; acc[4 + j][1] += pv * vv.y;
            acc[4 + j][2] += pv * vv.z; acc[4 + j][3] += pv * vv.w;
        }
    }

    for (int j = 0; j < 8; ++j) {
        red4[mq * 16 + dhq] =
            make_float4(acc[j][0], acc[j][1], acc[j][2], acc[j][3]);
        __syncthreads();
        if (tid < 64) {
            int dq = tid >> 2, x = tid & 3;
            float s = 0.f;
#pragma unroll
            for (int qq = 0; qq < 16; ++qq)
                s += ((const float*)&red4[qq * 16 + dq])[x];
            out[(size_t)(n0 + j) * DMODEL + h * 64 + tid] = s;
        }
        __syncthreads();
    }
}

// ---------------------------------------------------------------------------
extern "C" void kernel_launch(void* const* d_in, const int* in_sizes, int n_in,
                              void* d_out, int out_size, void* d_ws,
                              size_t ws_size, hipStream_t stream)
{
    const float* xq = (const float*)d_in[0];
    const float* xk = (const float*)d_in[1];
    const float* xv = (const float*)d_in[2];
    const float* xp = (const float*)d_in[3];
    const unsigned char* mask = (const unsigned char*)d_in[4];
    const float* Wq = (const float*)d_in[5];
    const float* bq = (const float*)d_in[6];
    const float* Wk = (const float*)d_in[7];
    const float* bk = (const float*)d_in[8];
    const float* Wv = (const float*)d_in[9];
    const float* bv = (const float*)d_in[10];
    const float* Wp = (const float*)d_in[11];
    const float* bp = (const float*)d_in[12];
    float* out = (float*)d_out;
    float* ws  = (float*)d_ws;

    proj_qkv  <<<192,  256, 0, stream>>>(xq, xk, xv, Wq, bq, Wk, bk, Wv, bv, ws);
    make_wpeff<<<512,  256, 0, stream>>>(Wp, ws);
    qk_scores <<<256,  256, 0, stream>>>(bp, ws);
    p_scores  <<<1024, 256, 0, stream>>>(xp, ws);
    softmax_av<<<256,  256, 0, stream>>>(mask, out, ws);
}

// Round 9
// 99.514 us; speedup vs baseline: 1.5793x; 1.1243x over previous
//
#include <hip/hip_runtime.h>
#include <math.h>

// Problem constants
#define DMODEL 256
#define NSEQ   512
#define MSEQ   512

// ws layout (float offsets)
#define WS_Q      0            // [512][256]
#define WS_K      131072       // [512][256]
#define WS_V      262144       // [512][256]
#define WS_WPE    393216       // [512][256][4]  (n, d, h)
#define WS_SQK    917504       // [4][512][512]  qk prescaled, then final scores (in-place)
// total floats = 1966080 -> 7.5 MB

typedef float v4f __attribute__((ext_vector_type(4)));

// ---------------------------------------------------------------------------
// Kernel A: q/k/v projections.  Y = X @ W^T + b   (fp32)
// grid = 3 * 64 blocks, 256 threads (thread = out col)
// ---------------------------------------------------------------------------
__global__ __launch_bounds__(256) void proj_qkv(
    const float* __restrict__ xq, const float* __restrict__ xk,
    const float* __restrict__ xv,
    const float* __restrict__ Wq, const float* __restrict__ bq,
    const float* __restrict__ Wk, const float* __restrict__ bk,
    const float* __restrict__ Wv, const float* __restrict__ bv,
    float* __restrict__ ws)
{
    int bid = blockIdx.x;
    int mat = bid >> 6;
    int rb  = bid & 63;
    const float* X; const float* W; const float* b; float* Y;
    if (mat == 0)      { X = xq; W = Wq; b = bq; Y = ws + WS_Q; }
    else if (mat == 1) { X = xk; W = Wk; b = bk; Y = ws + WS_K; }
    else               { X = xv; W = Wv; b = bv; Y = ws + WS_V; }

    int c  = threadIdx.x;
    int r0 = rb * 8;
    float acc[8];
    float bias = b[c];
#pragma unroll
    for (int r = 0; r < 8; ++r) acc[r] = bias;

    const float4* Wrow = (const float4*)(W + (size_t)c * DMODEL);
    for (int d4 = 0; d4 < 64; ++d4) {
        float4 w = Wrow[d4];
#pragma unroll
        for (int r = 0; r < 8; ++r) {
            float4 x = ((const float4*)(X + (size_t)(r0 + r) * DMODEL))[d4];
            acc[r] += w.x * x.x + w.y * x.y + w.z * x.z + w.w * x.w;
        }
    }
#pragma unroll
    for (int r = 0; r < 8; ++r)
        Y[(size_t)(r0 + r) * DMODEL + c] = acc[r];
}

// ---------------------------------------------------------------------------
// Kernel BC (fused): blocks 0..255  -> W'[n][d][h] for n = 2*bid, 2*bid+1
//                    blocks 256..511 -> sqk[h][n][m] = 0.125*(q·k + q·bp)
// Both halves depend only on proj output; fusing saves one launch drain.
// ---------------------------------------------------------------------------
__global__ __launch_bounds__(256) void wpeff_qk(
    const float* __restrict__ Wp, const float* __restrict__ bp,
    float* __restrict__ ws)
{
    int bid = blockIdx.x;
    int tid = threadIdx.x;

    if (bid < 256) {
        // ---- make_wpeff (R1 version: 2 n per block, thread = d) ----
        const float* q   = ws + WS_Q;
        float*       wpe = ws + WS_WPE;
        int n0 = bid * 2;
        int d  = tid;

        const float* q0 = q + (size_t)n0 * DMODEL;
        const float* q1 = q0 + DMODEL;

        float acc0[4] = {0.f, 0.f, 0.f, 0.f};
        float acc1[4] = {0.f, 0.f, 0.f, 0.f};
#pragma unroll
        for (int h = 0; h < 4; ++h) {
#pragma unroll 8
            for (int dh = 0; dh < 64; ++dh) {
                int c = h * 64 + dh;
                float w = Wp[(size_t)c * DMODEL + d];
                acc0[h] += q0[c] * w;
                acc1[h] += q1[c] * w;
            }
        }
        *(float4*)&wpe[(size_t)n0 * 1024 + d * 4] =
            make_float4(acc0[0], acc0[1], acc0[2], acc0[3]);
        *(float4*)&wpe[(size_t)(n0 + 1) * 1024 + d * 4] =
            make_float4(acc1[0], acc1[1], acc1[2], acc1[3]);
    } else {
        // ---- qk_scores (write-only, prescaled) ----
        const float* q   = ws + WS_Q;
        const float* k   = ws + WS_K;
        float*       sqk = ws + WS_SQK;

        int b2  = bid - 256;
        int h   = b2 >> 6;
        int g   = b2 & 63;
        int n0  = g * 8;

        __shared__ float qls[8][64];
        __shared__ float qb[8];

        if (tid < 128) {
            int row = tid >> 4, col = (tid & 15) * 4;
            *(float4*)&qls[row][col] =
                *(const float4*)&q[(size_t)(n0 + row) * DMODEL + h * 64 + col];
        }
        __syncthreads();
        if (tid < 8) {
            float s = 0.f;
            for (int dh = 0; dh < 64; ++dh) s += qls[tid][dh] * bp[h * 64 + dh];
            qb[tid] = s;
        }
        __syncthreads();

        const float* ka = k + (size_t)tid * DMODEL + h * 64;
        const float* kb = ka + (size_t)256 * DMODEL;
        float acca[8] = {};
        float accb[8] = {};
#pragma unroll 4
        for (int d4 = 0; d4 < 16; ++d4) {
            float4 xa = *(const float4*)(ka + d4 * 4);
            float4 xb = *(const float4*)(kb + d4 * 4);
#pragma unroll
            for (int j = 0; j < 8; ++j) {
                float4 qq = *(const float4*)&qls[j][d4 * 4];
                acca[j] += xa.x * qq.x + xa.y * qq.y + xa.z * qq.z + xa.w * qq.w;
                accb[j] += xb.x * qq.x + xb.y * qq.y + xb.z * qq.z + xb.w * qq.w;
            }
        }
#pragma unroll
        for (int j = 0; j < 8; ++j) {
            size_t base = (size_t)h * 262144 + (size_t)(n0 + j) * MSEQ;
            sqk[base + tid]       = 0.125f * (acca[j] + qb[j]);
            sqk[base + tid + 256] = 0.125f * (accb[j] + qb[j]);
        }
    }
}

// ---------------------------------------------------------------------------
// Kernel D: HBM-streaming kernel — R1's best-measured pattern verbatim.
// thread = one m-row (1 KB), plain float4 loads, unroll 8; W'[n] staged in
// LDS (4 KB, all compute reads broadcast). Epilogue: sqk += 0.125*(p·W').
// grid = 1024 blocks (n, m-half), 256 threads.
// ---------------------------------------------------------------------------
__global__ __launch_bounds__(256) void p_scores(
    const float* __restrict__ Xp, float* __restrict__ ws)
{
    const float* wpe = ws + WS_WPE;
    float*       sqk = ws + WS_SQK;

    int n = blockIdx.x >> 1;
    int m = (blockIdx.x & 1) * 256 + threadIdx.x;

    __shared__ float4 wl[256];  // wl[d4*4+c] = W'[n][d=4*d4+c][h0..h3]
    wl[threadIdx.x] = ((const float4*)(wpe + (size_t)n * 1024))[threadIdx.x];
    __syncthreads();

    const float4* xrow =
        (const float4*)(Xp + (size_t)((size_t)n * MSEQ + m) * DMODEL);
    float4 acc = make_float4(0.f, 0.f, 0.f, 0.f);
#pragma unroll 8
    for (int d4 = 0; d4 < 64; ++d4) {
        float4 x  = xrow[d4];
        float4 w0 = wl[d4 * 4 + 0];
        float4 w1 = wl[d4 * 4 + 1];
        float4 w2 = wl[d4 * 4 + 2];
        float4 w3 = wl[d4 * 4 + 3];
        acc.x += x.x * w0.x + x.y * w1.x + x.z * w2.x + x.w * w3.x;
        acc.y += x.x * w0.y + x.y * w1.y + x.z * w2.y + x.w * w3.y;
        acc.z += x.x * w0.z + x.y * w1.z + x.z * w2.z + x.w * w3.z;
        acc.w += x.x * w0.w + x.y * w1.w + x.z * w2.w + x.w * w3.w;
    }
    size_t ob = (size_t)n * MSEQ + m;
    sqk[0 * 262144 + ob] += 0.125f * acc.x;
    sqk[1 * 262144 + ob] += 0.125f * acc.y;
    sqk[2 * 262144 + ob] += 0.125f * acc.z;
    sqk[3 * 262144 + ob] += 0.125f * acc.w;
}

// ---------------------------------------------------------------------------
// Kernel E: masked softmax over m + attn @ v, writes final output.
// (R1 version verbatim)
// ---------------------------------------------------------------------------
__global__ __launch_bounds__(256) void softmax_av(
    const unsigned char* __restrict__ mask,
    float* __restrict__ out, float* __restrict__ ws)
{
    const float* v      = ws + WS_V;
    const float* scores = ws + WS_SQK;

    int bid = blockIdx.x;
    int h   = bid >> 6;
    int g   = bid & 63;
    int n0  = g * 8;

    __shared__ float  pl[MSEQ * 8];   // [m][j]  16 KB
    __shared__ float4 red4[256];      // reduce scratch 4 KB
    __shared__ float  wred[4];

    int tid  = threadIdx.x;
    int lane = tid & 63, wv = tid >> 6;

    for (int j = 0; j < 8; ++j) {
        int n = n0 + j;
        const float* srow = scores + (size_t)h * 262144 + (size_t)n * MSEQ;
        float s0 = srow[tid];
        float s1 = srow[tid + 256];
        if (mask[tid])       s0 = -INFINITY;
        if (mask[tid + 256]) s1 = -INFINITY;

        float mx = fmaxf(s0, s1);
#pragma unroll
        for (int off = 32; off; off >>= 1) mx = fmaxf(mx, __shfl_xor(mx, off));
        if (lane == 0) wred[wv] = mx;
        __syncthreads();
        mx = fmaxf(fmaxf(wred[0], wred[1]), fmaxf(wred[2], wred[3]));

        float e0 = __expf(s0 - mx);
        float e1 = __expf(s1 - mx);
        float sm = e0 + e1;
#pragma unroll
        for (int off = 32; off; off >>= 1) sm += __shfl_xor(sm, off);
        __syncthreads();
        if (lane == 0) wred[wv] = sm;
        __syncthreads();
        sm = wred[0] + wred[1] + wred[2] + wred[3];
        float rinv = 1.0f / sm;

        pl[(size_t)tid * 8 + j]         = e0 * rinv;
        pl[(size_t)(tid + 256) * 8 + j] = e1 * rinv;
        __syncthreads();
    }

    // AV: thread = (dhq 0..15, mq 0..15); each covers 32 m values.
    int dhq = tid & 15, mq = tid >> 4;
    float acc[8][4] = {};
    for (int i = 0; i < 32; ++i) {
        int m = mq * 32 + i;
        float4 vv = *(const float4*)&v[(size_t)m * DMODEL + h * 64 + dhq * 4];
        float4 pa = *(const float4*)&pl[m * 8];
        float4 pb = *(const float4*)&pl[m * 8 + 4];
#pragma unroll
        for (int j = 0; j < 4; ++j) {
            float pv = (&pa.x)[j];
            acc[j][0] += pv * vv.x; acc[j][1] += pv * vv.y;
            acc[j][2] += pv * vv.z; acc[j][3] += pv * vv.w;
        }
#pragma unroll
        for (int j = 0; j < 4; ++j) {
            float pv = (&pb.x)[j];
            acc[4 + j][0] += pv * vv.x; acc[4 + j][1] += pv * vv.y;
            acc[4 + j][2] += pv * vv.z; acc[4 + j][3] += pv * vv.w;
        }
    }

    for (int j = 0; j < 8; ++j) {
        red4[mq * 16 + dhq] =
            make_float4(acc[j][0], acc[j][1], acc[j][2], acc[j][3]);
        __syncthreads();
        if (tid < 64) {
            int dq = tid >> 2, x = tid & 3;
            float s = 0.f;
#pragma unroll
            for (int qq = 0; qq < 16; ++qq)
                s += ((const float*)&red4[qq * 16 + dq])[x];
            out[(size_t)(n0 + j) * DMODEL + h * 64 + tid] = s;
        }
        __syncthreads();
    }
}

// ---------------------------------------------------------------------------
extern "C" void kernel_launch(void* const* d_in, const int* in_sizes, int n_in,
                              void* d_out, int out_size, void* d_ws,
                              size_t ws_size, hipStream_t stream)
{
    const float* xq = (const float*)d_in[0];
    const float* xk = (const float*)d_in[1];
    const float* xv = (const float*)d_in[2];
    const float* xp = (const float*)d_in[3];
    const unsigned char* mask = (const unsigned char*)d_in[4];
    const float* Wq = (const float*)d_in[5];
    const float* bq = (const float*)d_in[6];
    const float* Wk = (const float*)d_in[7];
    const float* bk = (const float*)d_in[8];
    const float* Wv = (const float*)d_in[9];
    const float* bv = (const float*)d_in[10];
    const float* Wp = (const float*)d_in[11];
    const float* bp = (const float*)d_in[12];
    float* out = (float*)d_out;
    float* ws  = (float*)d_ws;

    proj_qkv  <<<192,  256, 0, stream>>>(xq, xk, xv, Wq, bq, Wk, bk, Wv, bv, ws);
    wpeff_qk  <<<512,  256, 0, stream>>>(Wp, bp, ws);
    p_scores  <<<1024, 256, 0, stream>>>(xp, ws);
    softmax_av<<<256,  256, 0, stream>>>(mask, out, ws);
}